// Round 1
// baseline (115.417 us; speedup 1.0000x reference)
//
#include <hip/hip_runtime.h>
#include <hip/hip_bf16.h>

#define IN_DIM  1024
#define OUT_DIM 1024
#define HID     4
#define BATCH   8192
#define NCOL    (OUT_DIM * HID)   // 4096 GEMM N dimension

typedef __bf16 bf16x8 __attribute__((ext_vector_type(8)));
typedef float  f32x4  __attribute__((ext_vector_type(4)));

__device__ __forceinline__ unsigned short f2bf(float f) {
  union { float f; unsigned int u; } v; v.f = f;
  unsigned int u = v.u;
  u += 0x7FFFu + ((u >> 16) & 1u);   // round-to-nearest-even
  return (unsigned short)(u >> 16);
}

// ---- x: f32 [8192][1024] -> bf16 [8192][1024]. One float4 per thread. ----
__global__ __launch_bounds__(256) void cvt_x_kernel(const float4* __restrict__ in,
                                                    ushort4* __restrict__ out) {
  int i = blockIdx.x * 256 + threadIdx.x;   // grid sized exactly: no bounds check
  float4 v = in[i];
  ushort4 o;
  o.x = f2bf(v.x); o.y = f2bf(v.y); o.z = f2bf(v.z); o.w = f2bf(v.w);
  out[i] = o;
}

// ---- W1: f32 (O,I,H) -> bf16 W1t[(o*4+h)][i]  (N x K row-major) ----
// Block handles one (o,h) slice of 1024 i's; writes coalesced ushort4.
// XCD-grouping remap so the 4 h-blocks of the same o share an XCD L2.
__global__ __launch_bounds__(256) void cvt_w1t_kernel(const float* __restrict__ W1,
                                                      ushort4* __restrict__ out) {
  int b = blockIdx.x;
  int g = ((b & 7) * ((int)gridDim.x >> 3) + (b >> 3)) * 256 + threadIdx.x;
  int i4 = g & 255;          // ushort4 index along K
  int oh = g >> 8;           // 0..4095
  int h = oh & 3, o = oh >> 2;
  const float* src = W1 + (size_t)o * 4096 + h;
  ushort4 r;
  r.x = f2bf(src[(i4 * 4 + 0) * 4]);
  r.y = f2bf(src[(i4 * 4 + 1) * 4]);
  r.z = f2bf(src[(i4 * 4 + 2) * 4]);
  r.w = f2bf(src[(i4 * 4 + 3) * 4]);
  out[(size_t)oh * 256 + i4] = r;
}

// ---- main GEMM + fused MLP epilogue ----
#define BM 128
#define BN 128
#define BK 32

__device__ __forceinline__ void gload16(const void* g, void* l) {
  __builtin_amdgcn_global_load_lds(
      (const __attribute__((address_space(1))) unsigned int*)g,
      (__attribute__((address_space(3))) unsigned int*)l, 16, 0, 0);
}

__global__ __launch_bounds__(256, 2) void mlp_gemm_kernel(
    const unsigned short* __restrict__ A,   // xbf   [8192][1024]
    const unsigned short* __restrict__ Bm,  // w1t   [4096][1024]
    const float* __restrict__ b1f,          // flat [4096] = per GEMM column
    const float* __restrict__ w2f,          // flat [4096] = per GEMM column
    const float* __restrict__ b2,           // [1024]
    float* __restrict__ out) {              // [8192][1024]
  __shared__ __align__(16) unsigned short sA[BM * BK];
  __shared__ __align__(16) unsigned short sB[BN * BK];

  int b = blockIdx.x;
  int wg = (b & 7) * ((int)gridDim.x >> 3) + (b >> 3);  // XCD swizzle (2048 % 8 == 0)
  int bx = wg & 31;    // N tile index (4096/128)
  int by = wg >> 5;    // M tile index (8192/128)
  int t = threadIdx.x;
  int lane = t & 63;
  int wid = t >> 6;
  int wr = wid >> 1, wc = wid & 1;   // 2x2 waves, each owns 64x64

  const unsigned short* aBase = A + (size_t)by * BM * IN_DIM;
  const unsigned short* bBase = Bm + (size_t)bx * BN * IN_DIM;
  int r  = t >> 2;          // staging row 0..63
  int kc = (t & 3) * 8;     // staging k-offset (8 bf16 = 16B)

  const f32x4 fzero = {0.f, 0.f, 0.f, 0.f};
  f32x4 acc[4][4];
#pragma unroll
  for (int m = 0; m < 4; ++m)
#pragma unroll
    for (int n = 0; n < 4; ++n) acc[m][n] = fzero;

  int frow = lane & 15;          // fragment row/col within 16
  int koff = (lane >> 4) * 8;    // fragment k offset

  for (int kb = 0; kb < IN_DIM; kb += BK) {
    gload16(aBase + (size_t)r * IN_DIM + kb + kc,        &sA[t * 8]);
    gload16(aBase + (size_t)(r + 64) * IN_DIM + kb + kc, &sA[2048 + t * 8]);
    gload16(bBase + (size_t)r * IN_DIM + kb + kc,        &sB[t * 8]);
    gload16(bBase + (size_t)(r + 64) * IN_DIM + kb + kc, &sB[2048 + t * 8]);
    __syncthreads();   // drains vmcnt -> staging visible

    bf16x8 af[4], bfr[4];
#pragma unroll
    for (int m = 0; m < 4; ++m)
      af[m] = *(const bf16x8*)(&sA[(wr * 64 + m * 16 + frow) * BK + koff]);
#pragma unroll
    for (int n = 0; n < 4; ++n)
      bfr[n] = *(const bf16x8*)(&sB[(wc * 64 + n * 16 + frow) * BK + koff]);
#pragma unroll
    for (int m = 0; m < 4; ++m)
#pragma unroll
      for (int n = 0; n < 4; ++n)
        acc[m][n] = __builtin_amdgcn_mfma_f32_16x16x32_bf16(af[m], bfr[n], acc[m][n], 0, 0, 0);
    __syncthreads();   // protect LDS before next stage
  }

  // Epilogue: C/D layout col=lane&15, row=(lane>>4)*4+j (verified m89).
  // col -> (o = col>>2, h = col&3); b1/w2 are flat per-column vectors.
  int row0 = by * BM + wr * 64 + (lane >> 4) * 4;
  int col0 = bx * BN + wc * 64 + (lane & 15);
#pragma unroll
  for (int n = 0; n < 4; ++n) {
    int col = col0 + n * 16;
    float b1v = b1f[col];
    float w2v = w2f[col];
    int o = col >> 2;
    float b2v = b2[o];
#pragma unroll
    for (int m = 0; m < 4; ++m) {
#pragma unroll
      for (int j = 0; j < 4; ++j) {
        float v = acc[m][n][j] + b1v;
        v = (v >= 0.f) ? v : 0.1f * v;   // LeakyReLU(0.1)
        v *= w2v;
        v += __shfl_xor(v, 1);           // sum the 4 hidden units
        v += __shfl_xor(v, 2);           // (lanes l, l^1, l^2, l^3 share o)
        if ((lane & 3) == 0)
          out[(size_t)(row0 + m * 16 + j) * OUT_DIM + o] = v + b2v;
      }
    }
  }
}

// ---- safety fallback (pure f32, used only if d_ws is too small) ----
__global__ __launch_bounds__(256) void fallback_kernel(
    const float* __restrict__ x, const float* __restrict__ W1,
    const float* __restrict__ b1, const float* __restrict__ W2,
    const float* __restrict__ b2, float* __restrict__ out) {
  int idx = blockIdx.x * 256 + threadIdx.x;
  if (idx >= BATCH * OUT_DIM) return;
  int bb = idx >> 10, o = idx & 1023;
  const float4* w1p = (const float4*)(W1 + (size_t)o * 4096);
  const float*  xp  = x + (size_t)bb * 1024;
  float4 acc = *(const float4*)(b1 + o * 4);
  for (int i = 0; i < 1024; ++i) {
    float xv = xp[i];
    float4 w = w1p[i];
    acc.x += xv * w.x; acc.y += xv * w.y; acc.z += xv * w.z; acc.w += xv * w.w;
  }
  float4 w2 = *(const float4*)(W2 + o * 4);
  float r = b2[o];
  r += ((acc.x >= 0.f) ? acc.x : 0.1f * acc.x) * w2.x;
  r += ((acc.y >= 0.f) ? acc.y : 0.1f * acc.y) * w2.y;
  r += ((acc.z >= 0.f) ? acc.z : 0.1f * acc.z) * w2.z;
  r += ((acc.w >= 0.f) ? acc.w : 0.1f * acc.w) * w2.w;
  out[(size_t)bb * OUT_DIM + o] = r;
}

extern "C" void kernel_launch(void* const* d_in, const int* in_sizes, int n_in,
                              void* d_out, int out_size, void* d_ws, size_t ws_size,
                              hipStream_t stream) {
  const float* x  = (const float*)d_in[0];
  const float* W1 = (const float*)d_in[1];
  const float* b1 = (const float*)d_in[2];
  const float* W2 = (const float*)d_in[3];
  const float* b2 = (const float*)d_in[4];
  float* out = (float*)d_out;

  size_t need = (size_t)BATCH * IN_DIM * 2 + (size_t)NCOL * IN_DIM * 2;  // 25.2 MB
  if (ws_size >= need) {
    unsigned short* xbf = (unsigned short*)d_ws;
    unsigned short* w1t = xbf + (size_t)BATCH * IN_DIM;
    cvt_x_kernel<<<(BATCH * IN_DIM / 4) / 256, 256, 0, stream>>>((const float4*)x, (ushort4*)xbf);
    cvt_w1t_kernel<<<(NCOL * IN_DIM / 4) / 256, 256, 0, stream>>>(W1, (ushort4*)w1t);
    mlp_gemm_kernel<<<(BATCH / BM) * (NCOL / BN), 256, 0, stream>>>(xbf, w1t, b1, W2, b2, out);
  } else {
    fallback_kernel<<<(BATCH * OUT_DIM + 255) / 256, 256, 0, stream>>>(x, W1, b1, W2, b2, out);
  }
}

// Round 2
// 107.489 us; speedup vs baseline: 1.0738x; 1.0738x over previous
//
#include <hip/hip_runtime.h>
#include <hip/hip_bf16.h>

#define IN_DIM  1024
#define OUT_DIM 1024
#define HID     4
#define BATCH   8192
#define NCOL    (OUT_DIM * HID)   // 4096 GEMM N dimension

typedef __bf16 bf16x8 __attribute__((ext_vector_type(8)));
typedef float  f32x4  __attribute__((ext_vector_type(4)));

__device__ __forceinline__ unsigned short f2bf(float f) {
  union { float f; unsigned int u; } v; v.f = f;
  unsigned int u = v.u;
  u += 0x7FFFu + ((u >> 16) & 1u);   // round-to-nearest-even
  return (unsigned short)(u >> 16);
}

// ---- x: f32 [8192][1024] -> bf16 [8192][1024] ----
__global__ __launch_bounds__(256) void cvt_x_kernel(const float4* __restrict__ in,
                                                    ushort4* __restrict__ out) {
  int i = blockIdx.x * 256 + threadIdx.x;
  float4 v = in[i];
  ushort4 o;
  o.x = f2bf(v.x); o.y = f2bf(v.y); o.z = f2bf(v.z); o.w = f2bf(v.w);
  out[i] = o;
}

// ---- W1: f32 (O,I,H) -> bf16 W1t[(o*4+h)][i]  (N x K row-major) ----
__global__ __launch_bounds__(256) void cvt_w1t_kernel(const float* __restrict__ W1,
                                                      ushort4* __restrict__ out) {
  int b = blockIdx.x;
  int g = ((b & 7) * ((int)gridDim.x >> 3) + (b >> 3)) * 256 + threadIdx.x;
  int i4 = g & 255;
  int oh = g >> 8;
  int h = oh & 3, o = oh >> 2;
  const float* src = W1 + (size_t)o * 4096 + h;
  ushort4 r;
  r.x = f2bf(src[(i4 * 4 + 0) * 4]);
  r.y = f2bf(src[(i4 * 4 + 1) * 4]);
  r.z = f2bf(src[(i4 * 4 + 2) * 4]);
  r.w = f2bf(src[(i4 * 4 + 3) * 4]);
  out[(size_t)oh * 256 + i4] = r;
}

__device__ __forceinline__ void gload16(const void* g, void* l) {
  __builtin_amdgcn_global_load_lds(
      (const __attribute__((address_space(1))) unsigned int*)g,
      (__attribute__((address_space(3))) unsigned int*)l, 16, 0, 0);
}

// ================= 256x256 / BK=64 8-phase GEMM + fused MLP epilogue ========
// 8 waves: 2(M) x 4(N); per-wave output 128x64 = acc[8][4] 16x16 frags.
// LDS 128 KiB: A: 2buf x 2half x [128][64] bf16 ; B: same at +32768 elems.
// Swizzle: 16B slot s_phys = s_log ^ (row&7). Staged via pre-swizzled global
// source (linear LDS dest, rule #21); read with same XOR.
// Per tile (K=64), 4 phases (quadrants m0n0, m0n1, m1n1, m1n0):
//   q0: ds_read A0(8)+B(8) | stage(next A-hi) | bar | lgkm0 | 16 MFMA | bar
//   q1:                      stage(t+2 B-lo)  | bar |       | 16 MFMA | bar
//   q2: ds_read A1(8)      | stage(t+2 B-hi)  | bar | lgkm0 | 16 MFMA | bar
//   q3:                      stage(t+2 A-lo)  | bar | 16 MFMA | vmcnt(6) | bar
// Slot-overwrite safety: B slots read only q0 (staged q1/q2 of +2 tile);
// A-lo read q0,q2 (staged q3); A-hi read q0,q2 (staged q0 into other buf).
__global__ __launch_bounds__(512, 2) void mlp_gemm_kernel(
    const unsigned short* __restrict__ A,   // xbf [8192][1024]
    const unsigned short* __restrict__ Bm,  // w1t [4096][1024]
    const float* __restrict__ b1f,          // [4096] per-column
    const float* __restrict__ w2f,          // [4096] per-column
    const float* __restrict__ b2,           // [1024]
    float* __restrict__ out) {              // [8192][1024]
  __shared__ __align__(16) unsigned short lds[65536];   // 128 KiB

  const int b = blockIdx.x;
  const int wgid = (b & 7) * 64 + (b >> 3);   // XCD swizzle (512 % 8 == 0)
  const int Cc = wgid >> 4, ii = wgid & 15;   // 16-wg chunks = 8M x 2N tiles
  const int by = (Cc & 3) * 8 + (ii >> 1);    // M tile 0..31
  const int bx = (Cc >> 2) * 2 + (ii & 1);    // N tile 0..15
  const int tileM = by * 256, tileN = bx * 256;

  const int t = threadIdx.x;
  const int lane = t & 63, wid = t >> 6;
  const int wm = wid >> 2, wn = wid & 3;

  // staging: thread t covers rows (t>>3) and (t>>3)+64 of a [128][64] half-tile
  const int sr = t >> 3;
  const int sc = ((t & 7) ^ (sr & 7)) << 3;   // inverse-swizzled source col
  const unsigned short* Asrc = A + (size_t)(tileM + sr) * IN_DIM + sc;
  const unsigned short* Bsrc = Bm + (size_t)(tileN + sr) * IN_DIM + sc;
  unsigned short* ldsw = lds;

  // half-tile stream: h -> tile T=h>>2, part h&3: 0=B-lo 1=B-hi 2=A-lo 3=A-hi
  auto stage = [&](int h) {
    if (h >= 64) return;
    int T = h >> 2, part = h & 3;
    int kb = T * 64;
    int half = part & 1;
    const unsigned short* g;
    unsigned short* l;
    if (part < 2) {
      g = Bsrc + (size_t)half * 128 * IN_DIM + kb;
      l = ldsw + 32768 + ((T & 1) * 2 + half) * 8192 + t * 8;
    } else {
      g = Asrc + (size_t)half * 128 * IN_DIM + kb;
      l = ldsw + ((T & 1) * 2 + half) * 8192 + t * 8;
    }
    gload16(g, l);
    gload16(g + 64 * IN_DIM, l + 4096);
  };

  // prologue: tile0 all 4 half-tiles + tile1 first 3
#pragma unroll
  for (int h = 0; h < 7; ++h) stage(h);
  asm volatile("s_waitcnt vmcnt(6)" ::: "memory");   // tile0 staged; 3 in flight
  __builtin_amdgcn_s_barrier();

  const int frow = lane & 15;
  const int koff = (lane >> 4) * 8;
  const int swz = (lane & 7) << 3;
  const int pc0 = koff ^ swz;          // k-slice 0 swizzled col (elems)
  const int pc1 = (32 + koff) ^ swz;   // k-slice 1

  const f32x4 fzero = {0.f, 0.f, 0.f, 0.f};
  f32x4 acc[8][4];
#pragma unroll
  for (int m = 0; m < 8; ++m)
#pragma unroll
    for (int n = 0; n < 4; ++n) acc[m][n] = fzero;

  bf16x8 a0[4][2], a1[4][2], bfr[4][2];

  for (int tt = 0; tt < 16; ++tt) {
    const unsigned short* sA = ldsw + ((tt & 1) * 2 + wm) * 8192;
    const unsigned short* sB = ldsw + 32768 + ((tt & 1) * 2 + (wn >> 1)) * 8192;
    const int brow0 = (wn & 1) * 64;

    // ---------------- q0: quadrant (m0, n0) ----------------
#pragma unroll
    for (int mf = 0; mf < 4; ++mf) {
      int r = mf * 16 + frow;
      a0[mf][0] = *(const bf16x8*)(sA + r * 64 + pc0);
      a0[mf][1] = *(const bf16x8*)(sA + r * 64 + pc1);
    }
#pragma unroll
    for (int nf = 0; nf < 4; ++nf) {
      int r = brow0 + nf * 16 + frow;
      bfr[nf][0] = *(const bf16x8*)(sB + r * 64 + pc0);
      bfr[nf][1] = *(const bf16x8*)(sB + r * 64 + pc1);
    }
    stage(4 * tt + 7);   // next tile's A-hi (other buffer)
    __builtin_amdgcn_s_barrier();
    asm volatile("s_waitcnt lgkmcnt(0)" ::: "memory");
    __builtin_amdgcn_sched_barrier(0);
    __builtin_amdgcn_s_setprio(1);
#pragma unroll
    for (int mf = 0; mf < 4; ++mf)
#pragma unroll
      for (int nf = 0; nf < 2; ++nf) {
        acc[mf][nf] = __builtin_amdgcn_mfma_f32_16x16x32_bf16(a0[mf][0], bfr[nf][0], acc[mf][nf], 0, 0, 0);
        acc[mf][nf] = __builtin_amdgcn_mfma_f32_16x16x32_bf16(a0[mf][1], bfr[nf][1], acc[mf][nf], 0, 0, 0);
      }
    __builtin_amdgcn_s_setprio(0);
    __builtin_amdgcn_s_barrier();

    // ---------------- q1: quadrant (m0, n1) ----------------
    stage(4 * tt + 8);   // tile t+2 B-lo (this buffer; B read only at q0)
    __builtin_amdgcn_s_barrier();
    __builtin_amdgcn_s_setprio(1);
#pragma unroll
    for (int mf = 0; mf < 4; ++mf)
#pragma unroll
      for (int nf = 2; nf < 4; ++nf) {
        acc[mf][nf] = __builtin_amdgcn_mfma_f32_16x16x32_bf16(a0[mf][0], bfr[nf][0], acc[mf][nf], 0, 0, 0);
        acc[mf][nf] = __builtin_amdgcn_mfma_f32_16x16x32_bf16(a0[mf][1], bfr[nf][1], acc[mf][nf], 0, 0, 0);
      }
    __builtin_amdgcn_s_setprio(0);
    __builtin_amdgcn_s_barrier();

    // ---------------- q2: quadrant (m1, n1) ----------------
#pragma unroll
    for (int mf = 0; mf < 4; ++mf) {
      int r = 64 + mf * 16 + frow;
      a1[mf][0] = *(const bf16x8*)(sA + r * 64 + pc0);
      a1[mf][1] = *(const bf16x8*)(sA + r * 64 + pc1);
    }
    stage(4 * tt + 9);   // tile t+2 B-hi
    __builtin_amdgcn_s_barrier();
    asm volatile("s_waitcnt lgkmcnt(0)" ::: "memory");
    __builtin_amdgcn_sched_barrier(0);
    __builtin_amdgcn_s_setprio(1);
#pragma unroll
    for (int mf = 0; mf < 4; ++mf)
#pragma unroll
      for (int nf = 2; nf < 4; ++nf) {
        acc[4 + mf][nf] = __builtin_amdgcn_mfma_f32_16x16x32_bf16(a1[mf][0], bfr[nf][0], acc[4 + mf][nf], 0, 0, 0);
        acc[4 + mf][nf] = __builtin_amdgcn_mfma_f32_16x16x32_bf16(a1[mf][1], bfr[nf][1], acc[4 + mf][nf], 0, 0, 0);
      }
    __builtin_amdgcn_s_setprio(0);
    __builtin_amdgcn_s_barrier();

    // ---------------- q3: quadrant (m1, n0) ----------------
    stage(4 * tt + 10);  // tile t+2 A-lo (read q0/q2 this tile -> safe at q3)
    __builtin_amdgcn_s_barrier();
    __builtin_amdgcn_s_setprio(1);
#pragma unroll
    for (int mf = 0; mf < 4; ++mf)
#pragma unroll
      for (int nf = 0; nf < 2; ++nf) {
        acc[4 + mf][nf] = __builtin_amdgcn_mfma_f32_16x16x32_bf16(a1[mf][0], bfr[nf][0], acc[4 + mf][nf], 0, 0, 0);
        acc[4 + mf][nf] = __builtin_amdgcn_mfma_f32_16x16x32_bf16(a1[mf][1], bfr[nf][1], acc[4 + mf][nf], 0, 0, 0);
      }
    __builtin_amdgcn_s_setprio(0);
    if (tt < 14)       asm volatile("s_waitcnt vmcnt(6)" ::: "memory");  // next tile staged
    else if (tt == 14) asm volatile("s_waitcnt vmcnt(0)" ::: "memory");  // tail drain
    __builtin_amdgcn_s_barrier();
  }

  // Epilogue: C/D layout col=lane&15, row=(lane>>4)*4+j (m89).
  const int row0 = tileM + wm * 128 + (lane >> 4) * 4;
  const int col0 = tileN + wn * 64 + frow;
#pragma unroll
  for (int nf = 0; nf < 4; ++nf) {
    int col = col0 + nf * 16;
    float b1v = b1f[col];
    float w2v = w2f[col];
    int o = col >> 2;
    float b2v = b2[o];
#pragma unroll
    for (int mf = 0; mf < 8; ++mf) {
#pragma unroll
      for (int j = 0; j < 4; ++j) {
        float v = acc[mf][nf][j] + b1v;
        v = (v >= 0.f) ? v : 0.1f * v;   // LeakyReLU(0.1)
        v *= w2v;
        v += __shfl_xor(v, 1);           // sum 4 hidden units (lanes share o)
        v += __shfl_xor(v, 2);
        if ((lane & 3) == 0)
          out[(size_t)(row0 + mf * 16 + j) * OUT_DIM + o] = v + b2v;
      }
    }
  }
}

// ---- safety fallback (pure f32, used only if d_ws is too small) ----
__global__ __launch_bounds__(256) void fallback_kernel(
    const float* __restrict__ x, const float* __restrict__ W1,
    const float* __restrict__ b1, const float* __restrict__ W2,
    const float* __restrict__ b2, float* __restrict__ out) {
  int idx = blockIdx.x * 256 + threadIdx.x;
  if (idx >= BATCH * OUT_DIM) return;
  int bb = idx >> 10, o = idx & 1023;
  const float4* w1p = (const float4*)(W1 + (size_t)o * 4096);
  const float*  xp  = x + (size_t)bb * 1024;
  float4 acc = *(const float4*)(b1 + o * 4);
  for (int i = 0; i < 1024; ++i) {
    float xv = xp[i];
    float4 w = w1p[i];
    acc.x += xv * w.x; acc.y += xv * w.y; acc.z += xv * w.z; acc.w += xv * w.w;
  }
  float4 w2 = *(const float4*)(W2 + o * 4);
  float r = b2[o];
  r += ((acc.x >= 0.f) ? acc.x : 0.1f * acc.x) * w2.x;
  r += ((acc.y >= 0.f) ? acc.y : 0.1f * acc.y) * w2.y;
  r += ((acc.z >= 0.f) ? acc.z : 0.1f * acc.z) * w2.z;
  r += ((acc.w >= 0.f) ? acc.w : 0.1f * acc.w) * w2.w;
  out[(size_t)bb * OUT_DIM + o] = r;
}

extern "C" void kernel_launch(void* const* d_in, const int* in_sizes, int n_in,
                              void* d_out, int out_size, void* d_ws, size_t ws_size,
                              hipStream_t stream) {
  const float* x  = (const float*)d_in[0];
  const float* W1 = (const float*)d_in[1];
  const float* b1 = (const float*)d_in[2];
  const float* W2 = (const float*)d_in[3];
  const float* b2 = (const float*)d_in[4];
  float* out = (float*)d_out;

  size_t need = (size_t)BATCH * IN_DIM * 2 + (size_t)NCOL * IN_DIM * 2;  // 25.2 MB
  if (ws_size >= need) {
    unsigned short* xbf = (unsigned short*)d_ws;
    unsigned short* w1t = xbf + (size_t)BATCH * IN_DIM;
    cvt_x_kernel<<<(BATCH * IN_DIM / 4) / 256, 256, 0, stream>>>((const float4*)x, (ushort4*)xbf);
    cvt_w1t_kernel<<<(NCOL * IN_DIM / 4) / 256, 256, 0, stream>>>(W1, (ushort4*)w1t);
    mlp_gemm_kernel<<<(BATCH / 256) * (NCOL / 256), 512, 0, stream>>>(xbf, w1t, b1, W2, b2, out);
  } else {
    fallback_kernel<<<(BATCH * OUT_DIM + 255) / 256, 256, 0, stream>>>(x, W1, b1, W2, b2, out);
  }
}

// Round 3
// 105.622 us; speedup vs baseline: 1.0927x; 1.0177x over previous
//
#include <hip/hip_runtime.h>
#include <hip/hip_bf16.h>

#define IN_DIM  1024
#define OUT_DIM 1024
#define HID     4
#define BATCH   8192
#define NCOL    (OUT_DIM * HID)   // 4096 = GEMM M dimension (oh), N = 8192 (batch)

typedef __bf16 bf16x8 __attribute__((ext_vector_type(8)));
typedef float  f32x4  __attribute__((ext_vector_type(4)));

__device__ __forceinline__ unsigned short f2bf(float f) {
  union { float f; unsigned int u; } v; v.f = f;
  unsigned int u = v.u;
  u += 0x7FFFu + ((u >> 16) & 1u);   // round-to-nearest-even
  return (unsigned short)(u >> 16);
}

// ---- x: f32 [8192][1024] -> bf16 [8192][1024] ----
__global__ __launch_bounds__(256) void cvt_x_kernel(const float4* __restrict__ in,
                                                    ushort4* __restrict__ out) {
  int i = blockIdx.x * 256 + threadIdx.x;
  float4 v = in[i];
  ushort4 o;
  o.x = f2bf(v.x); o.y = f2bf(v.y); o.z = f2bf(v.z); o.w = f2bf(v.w);
  out[i] = o;
}

// ---- W1: f32 (O,I,H) -> bf16 W1t[(o*4+h)][i]  (M x K row-major) ----
__global__ __launch_bounds__(256) void cvt_w1t_kernel(const float* __restrict__ W1,
                                                      ushort4* __restrict__ out) {
  int b = blockIdx.x;
  int g = ((b & 7) * ((int)gridDim.x >> 3) + (b >> 3)) * 256 + threadIdx.x;
  int i4 = g & 255;
  int oh = g >> 8;
  int h = oh & 3, o = oh >> 2;
  const float* src = W1 + (size_t)o * 4096 + h;
  ushort4 r;
  r.x = f2bf(src[(i4 * 4 + 0) * 4]);
  r.y = f2bf(src[(i4 * 4 + 1) * 4]);
  r.z = f2bf(src[(i4 * 4 + 2) * 4]);
  r.w = f2bf(src[(i4 * 4 + 3) * 4]);
  out[(size_t)oh * 256 + i4] = r;
}

__device__ __forceinline__ void gload16(const void* g, void* l) {
  __builtin_amdgcn_global_load_lds(
      (const __attribute__((address_space(1))) unsigned int*)g,
      (__attribute__((address_space(3))) unsigned int*)l, 16, 0, 0);
}

// ============ transposed GEMM: C[oh][batch] = W1t x xbf^T, 128x128/BK=64 =====
// 4 waves (2 oh-halves x 2 batch-halves), per-wave 64x64 = acc[4][4].
// LDS 64 KiB = 2 bufs x (A[128][64] + B[128][64]) bf16  -> 2 blocks/CU.
// Swizzle: 16B slot phys = log ^ (row&7); staged via inverse-swizzled global
// source (linear LDS dest), read with same XOR. Quarter-wave bank analysis:
// slot depends only on lane>>4 -> 2-way (free), verified 0 conflicts in R2.
// One barrier + one vmcnt(0) per K-tile (true dbuf: read cur, stage nxt).
__global__ __launch_bounds__(256, 2) void mlp_gemm_kernel(
    const unsigned short* __restrict__ A,   // w1t [4096][1024]  (M = oh)
    const unsigned short* __restrict__ Bm,  // xbf [8192][1024]  (N = batch)
    const f32x4* __restrict__ b1v,          // [1024] float4 per o
    const f32x4* __restrict__ w2v,          // [1024] float4 per o
    const float* __restrict__ b2,           // [1024]
    float* __restrict__ out) {              // [8192][1024]
  __shared__ __align__(16) unsigned short lds[32768];   // 64 KiB

  const int bid = blockIdx.x;
  const int wg  = (bid & 7) * 256 + (bid >> 3);   // XCD chunking (2048 % 8 == 0)
  const int bm  = wg >> 6;                        // oh tile 0..31 (A panel stays in L2)
  const int bn  = wg & 63;                        // batch tile 0..63
  const int tileM = bm * 128, tileN = bn * 128;

  const int t = threadIdx.x;
  const int lane = t & 63, wid = t >> 6;
  const int wm = wid >> 1, wn = wid & 1;          // wave -> (oh-half, batch-half)
  const int frow = lane & 15, jq = lane >> 4;

  // staging geometry: thread t covers rows (t>>3)+{0,32,64,96}, 16B slot t&7
  const int sr = t >> 3;
  const int sc = ((t & 7) ^ (sr & 7)) * 8;        // inverse-swizzled source col (elems)
  const unsigned short* Abase = A  + (size_t)(tileM + sr) * IN_DIM + sc;
  const unsigned short* Bbase = Bm + (size_t)(tileN + sr) * IN_DIM + sc;

  auto stage = [&](int kt, int p) {               // stage K-tile kt into buffer p
    const int kb = kt * 64;
    unsigned short* lA = lds + p * 16384 + t * 8;
    unsigned short* lB = lA + 8192;
#pragma unroll
    for (int i = 0; i < 4; ++i) {
      gload16(Abase + (size_t)i * 32 * IN_DIM + kb, lA + i * 2048);
      gload16(Bbase + (size_t)i * 32 * IN_DIM + kb, lB + i * 2048);
    }
  };

  stage(0, 0);
  asm volatile("s_waitcnt vmcnt(0)" ::: "memory");
  __builtin_amdgcn_s_barrier();

  const f32x4 fzero = {0.f, 0.f, 0.f, 0.f};
  f32x4 acc[4][4];
#pragma unroll
  for (int m = 0; m < 4; ++m)
#pragma unroll
    for (int n = 0; n < 4; ++n) acc[m][n] = fzero;

  for (int kt = 0; kt < 16; ++kt) {
    const int cur = kt & 1;
    if (kt < 15) stage(kt + 1, cur ^ 1);          // issue prefetch first (latency)

    const unsigned short* aP = lds + cur * 16384;
    const unsigned short* bP = aP + 8192;
    bf16x8 af[4][2], bf_[4][2];
#pragma unroll
    for (int mf = 0; mf < 4; ++mf) {
      int row = wm * 64 + mf * 16 + frow;
      int base = row * 64;
      af[mf][0] = *(const bf16x8*)(aP + base + ((jq     ^ (row & 7)) * 8));
      af[mf][1] = *(const bf16x8*)(aP + base + (((4+jq) ^ (row & 7)) * 8));
    }
#pragma unroll
    for (int nf = 0; nf < 4; ++nf) {
      int row = wn * 64 + nf * 16 + frow;
      int base = row * 64;
      bf_[nf][0] = *(const bf16x8*)(bP + base + ((jq     ^ (row & 7)) * 8));
      bf_[nf][1] = *(const bf16x8*)(bP + base + (((4+jq) ^ (row & 7)) * 8));
    }
    asm volatile("s_waitcnt lgkmcnt(0)" ::: "memory");
    __builtin_amdgcn_sched_barrier(0);
    __builtin_amdgcn_s_setprio(1);
#pragma unroll
    for (int mf = 0; mf < 4; ++mf)
#pragma unroll
      for (int nf = 0; nf < 4; ++nf) {
        acc[mf][nf] = __builtin_amdgcn_mfma_f32_16x16x32_bf16(af[mf][0], bf_[nf][0], acc[mf][nf], 0, 0, 0);
        acc[mf][nf] = __builtin_amdgcn_mfma_f32_16x16x32_bf16(af[mf][1], bf_[nf][1], acc[mf][nf], 0, 0, 0);
      }
    __builtin_amdgcn_s_setprio(0);
    if (kt < 15) asm volatile("s_waitcnt vmcnt(0)" ::: "memory");
    __builtin_amdgcn_s_barrier();
  }

  // ---- fused epilogue, all in-register hidden-dot ----
  // C/D: col = lane&15 = batch_local, row = (lane>>4)*4 + j = oh_local.
  // oh_local = wm*64 + mf*16 + jq*4 + j  ->  o_loc = wm*16 + mf*4 + jq, h = j.
  float* LE = (float*)lds;                         // [128 batch][36] f32 (padded)
  const int obase = (tileM >> 2);
#pragma unroll
  for (int mf = 0; mf < 4; ++mf) {
    int o_loc = wm * 16 + mf * 4 + jq;
    f32x4 b1q = b1v[obase + o_loc];
    f32x4 w2q = w2v[obase + o_loc];
#pragma unroll
    for (int nf = 0; nf < 4; ++nf) {
      int bat = wn * 64 + nf * 16 + frow;
      f32x4 q = acc[mf][nf];
      float v = 0.f;
#pragma unroll
      for (int j = 0; j < 4; ++j) {
        float hj = q[j] + b1q[j];
        hj = (hj >= 0.f) ? hj : 0.1f * hj;         // LeakyReLU(0.1)
        v += hj * w2q[j];
      }
      LE[bat * 36 + o_loc] = v;
    }
  }
  __builtin_amdgcn_s_barrier();

  // coalesced store: block covers out[tileN..+128)[obase..+32)
  const int so = t & 31, srow0 = t >> 5;
  const float b2s = b2[obase + so];
  float* outB = out + (size_t)tileN * OUT_DIM + obase;
#pragma unroll
  for (int i = 0; i < 16; ++i) {
    int row = srow0 + i * 8;
    outB[(size_t)row * OUT_DIM + so] = LE[row * 36 + so] + b2s;
  }
}

// ---- safety fallback (pure f32, used only if d_ws is too small) ----
__global__ __launch_bounds__(256) void fallback_kernel(
    const float* __restrict__ x, const float* __restrict__ W1,
    const float* __restrict__ b1, const float* __restrict__ W2,
    const float* __restrict__ b2, float* __restrict__ out) {
  int idx = blockIdx.x * 256 + threadIdx.x;
  if (idx >= BATCH * OUT_DIM) return;
  int bb = idx >> 10, o = idx & 1023;
  const float4* w1p = (const float4*)(W1 + (size_t)o * 4096);
  const float*  xp  = x + (size_t)bb * 1024;
  float4 acc = *(const float4*)(b1 + o * 4);
  for (int i = 0; i < 1024; ++i) {
    float xv = xp[i];
    float4 w = w1p[i];
    acc.x += xv * w.x; acc.y += xv * w.y; acc.z += xv * w.z; acc.w += xv * w.w;
  }
  float4 w2 = *(const float4*)(W2 + o * 4);
  float r = b2[o];
  r += ((acc.x >= 0.f) ? acc.x : 0.1f * acc.x) * w2.x;
  r += ((acc.y >= 0.f) ? acc.y : 0.1f * acc.y) * w2.y;
  r += ((acc.z >= 0.f) ? acc.z : 0.1f * acc.z) * w2.z;
  r += ((acc.w >= 0.f) ? acc.w : 0.1f * acc.w) * w2.w;
  out[(size_t)bb * OUT_DIM + o] = r;
}

extern "C" void kernel_launch(void* const* d_in, const int* in_sizes, int n_in,
                              void* d_out, int out_size, void* d_ws, size_t ws_size,
                              hipStream_t stream) {
  const float* x  = (const float*)d_in[0];
  const float* W1 = (const float*)d_in[1];
  const float* b1 = (const float*)d_in[2];
  const float* W2 = (const float*)d_in[3];
  const float* b2 = (const float*)d_in[4];
  float* out = (float*)d_out;

  size_t need = (size_t)BATCH * IN_DIM * 2 + (size_t)NCOL * IN_DIM * 2;  // 25.2 MB
  if (ws_size >= need) {
    unsigned short* xbf = (unsigned short*)d_ws;
    unsigned short* w1t = xbf + (size_t)BATCH * IN_DIM;
    cvt_x_kernel<<<(BATCH * IN_DIM / 4) / 256, 256, 0, stream>>>((const float4*)x, (ushort4*)xbf);
    cvt_w1t_kernel<<<(NCOL * IN_DIM / 4) / 256, 256, 0, stream>>>(W1, (ushort4*)w1t);
    mlp_gemm_kernel<<<(NCOL / 128) * (BATCH / 128), 256, 0, stream>>>(
        w1t, xbf, (const f32x4*)b1, (const f32x4*)W2, b2, out);
  } else {
    fallback_kernel<<<(BATCH * OUT_DIM + 255) / 256, 256, 0, stream>>>(x, W1, b1, W2, b2, out);
  }
}

// Round 4
// 91.421 us; speedup vs baseline: 1.2625x; 1.1553x over previous
//
#include <hip/hip_runtime.h>
#include <hip/hip_bf16.h>

#define IN_DIM  1024
#define OUT_DIM 1024
#define HID     4
#define BATCH   8192
#define NCOL    (OUT_DIM * HID)   // 4096 = GEMM M dimension (oh), N = 8192 (batch)

typedef __bf16 bf16x8 __attribute__((ext_vector_type(8)));
typedef float  f32x4  __attribute__((ext_vector_type(4)));

__device__ __forceinline__ unsigned short f2bf(float f) {
  union { float f; unsigned int u; } v; v.f = f;
  unsigned int u = v.u;
  u += 0x7FFFu + ((u >> 16) & 1u);   // round-to-nearest-even
  return (unsigned short)(u >> 16);
}

// ---- x: f32 [8192][1024] -> bf16 [8192][1024] ----
__global__ __launch_bounds__(256) void cvt_x_kernel(const float4* __restrict__ in,
                                                    ushort4* __restrict__ out) {
  int i = blockIdx.x * 256 + threadIdx.x;
  float4 v = in[i];
  ushort4 o;
  o.x = f2bf(v.x); o.y = f2bf(v.y); o.z = f2bf(v.z); o.w = f2bf(v.w);
  out[i] = o;
}

// ---- W1: f32 (O,I,H) -> bf16 W1t[(o*4+h)][i]  (M x K row-major) ----
__global__ __launch_bounds__(256) void cvt_w1t_kernel(const float* __restrict__ W1,
                                                      ushort4* __restrict__ out) {
  int b = blockIdx.x;
  int g = ((b & 7) * ((int)gridDim.x >> 3) + (b >> 3)) * 256 + threadIdx.x;
  int i4 = g & 255;
  int oh = g >> 8;
  int h = oh & 3, o = oh >> 2;
  const float* src = W1 + (size_t)o * 4096 + h;
  ushort4 r;
  r.x = f2bf(src[(i4 * 4 + 0) * 4]);
  r.y = f2bf(src[(i4 * 4 + 1) * 4]);
  r.z = f2bf(src[(i4 * 4 + 2) * 4]);
  r.w = f2bf(src[(i4 * 4 + 3) * 4]);
  out[(size_t)oh * 256 + i4] = r;
}

__device__ __forceinline__ void gload16(const void* g, void* l) {
  __builtin_amdgcn_global_load_lds(
      (const __attribute__((address_space(1))) unsigned int*)g,
      (__attribute__((address_space(3))) unsigned int*)l, 16, 0, 0);
}

// ===== transposed GEMM: C[oh][batch] = W1t x xbf^T, tile 256Mx128N, BK=32 ====
// 4 waves 2(M-half)x2(N-half); per-wave 128x64 = acc[8][4] (AI 28 FLOP/LDS-B).
// LDS 72 KiB = 3 rotating bufs x (A[256][32] + B[128][32]) bf16 -> 2 blocks/CU.
// Prefetch depth 2: iter kt stages kt+2, waits vmcnt(6) = oldest stage done.
// Swizzle: 16B slot phys = log ^ (row&3); staged via inverse-swizzled global
// column (linear LDS dest), read back with same XOR -> conflict-free b128.
// XCD map: XCD x owns batch-tiles [8x,8x+8) (2 MB x-slice, L2-resident),
// sweeps oh-tiles bn-inner.
__global__ __launch_bounds__(256, 2) void mlp_gemm_kernel(
    const unsigned short* __restrict__ A,   // w1t [4096][1024]  (M = oh)
    const unsigned short* __restrict__ Bm,  // xbf [8192][1024]  (N = batch)
    const f32x4* __restrict__ b1v,          // [1024] float4 per o
    const f32x4* __restrict__ w2v,          // [1024] float4 per o
    const float* __restrict__ b2,           // [1024]
    float* __restrict__ out) {              // [8192][1024]
  __shared__ __align__(16) unsigned short lds[36864];   // 72 KiB

  const int bid = blockIdx.x;
  const int xcd = bid & 7, loc = bid >> 3;        // 128 blocks per XCD
  const int bm = loc >> 3;                        // oh tile 0..15 (bn-inner order)
  const int bn = xcd * 8 + (loc & 7);             // batch tile 0..63
  const int tileM = bm * 256, tileN = bn * 128;

  const int t = threadIdx.x;
  const int lane = t & 63, wid = t >> 6;
  const int wm = wid >> 1, wn = wid & 1;
  const int frow = lane & 15, jq = lane >> 4;

  // staging: thread t -> row sr = t>>2 (+64*i), 16B slot t&3 (linear dest)
  const int sr = t >> 2;
  const int sc = (((t & 3) ^ (sr & 3)) << 3);     // inverse-swizzled source col
  const unsigned short* Abase = A  + (size_t)(tileM + sr) * IN_DIM + sc;
  const unsigned short* Bbase = Bm + (size_t)(tileN + sr) * IN_DIM + sc;

  auto stage = [&](int kt, int p) {               // 6 x gload16 = 24 KB
    const int kb = kt * 32;
    unsigned short* lA = lds + p * 12288 + t * 8;
#pragma unroll
    for (int i = 0; i < 4; ++i)
      gload16(Abase + (size_t)i * 64 * IN_DIM + kb, lA + i * 2048);
#pragma unroll
    for (int i = 0; i < 2; ++i)
      gload16(Bbase + (size_t)i * 64 * IN_DIM + kb, lA + 8192 + i * 2048);
  };

  const f32x4 fzero = {0.f, 0.f, 0.f, 0.f};
  f32x4 acc[8][4];
#pragma unroll
  for (int m = 0; m < 8; ++m)
#pragma unroll
    for (int n = 0; n < 4; ++n) acc[m][n] = fzero;

  // fragment offsets (elems). row&3 == frow&3 for all frags -> one pslot.
  const int pslot = (jq ^ (frow & 3)) << 3;
  const int aoff = (wm * 128 + frow) * 32 + pslot;          // + mf*512
  const int boff = 8192 + (wn * 64 + frow) * 32 + pslot;    // + nf*512

  stage(0, 0);
  stage(1, 1);
  asm volatile("s_waitcnt vmcnt(6)" ::: "memory");   // stage(0) complete
  __builtin_amdgcn_s_barrier();

  // mode 0: stage kt+2 + vmcnt(6); 1: no stage, vmcnt(0); 2: tail, no wait
  auto ktile = [&](int kt, int pr, int ps, int mode) {
    if (mode == 0) stage(kt + 2, ps);
    const unsigned short* bufp = lds + pr * 12288;
    bf16x8 af[8], bfr[4];
#pragma unroll
    for (int mf = 0; mf < 8; ++mf)
      af[mf] = *(const bf16x8*)(bufp + aoff + mf * 512);
#pragma unroll
    for (int nf = 0; nf < 4; ++nf)
      bfr[nf] = *(const bf16x8*)(bufp + boff + nf * 512);
    asm volatile("s_waitcnt lgkmcnt(0)" ::: "memory");
    __builtin_amdgcn_sched_barrier(0);
    __builtin_amdgcn_s_setprio(1);
#pragma unroll
    for (int mf = 0; mf < 8; ++mf)
#pragma unroll
      for (int nf = 0; nf < 4; ++nf)
        acc[mf][nf] = __builtin_amdgcn_mfma_f32_16x16x32_bf16(af[mf], bfr[nf], acc[mf][nf], 0, 0, 0);
    __builtin_amdgcn_s_setprio(0);
    if (mode == 0)      asm volatile("s_waitcnt vmcnt(6)" ::: "memory");  // kt+1 staged
    else if (mode == 1) asm volatile("s_waitcnt vmcnt(0)" ::: "memory");  // drain
    __builtin_amdgcn_s_barrier();
  };

  for (int g = 0; g < 30; g += 3) {   // buffers rotate 0,1,2; stage target +2
    ktile(g,     0, 2, 0);
    ktile(g + 1, 1, 0, 0);
    ktile(g + 2, 2, 1, 0);
  }
  ktile(30, 0, 0, 1);
  ktile(31, 1, 0, 2);

  // ---- fused epilogue: in-register hidden-dot, LDS transpose, coalesced ----
  // C/D: col = lane&15 = batch_local, row = jq*4 + j = oh_local.
  // oh_local = wm*128 + mf*16 + jq*4 + j -> o_loc = wm*32 + mf*4 + jq, h = j.
  float* LE = (float*)lds;                        // [128 batch][68] f32
  const int obase = tileM >> 2;                   // block's o range: 64 values
#pragma unroll
  for (int mf = 0; mf < 8; ++mf) {
    int o_loc = wm * 32 + mf * 4 + jq;
    f32x4 b1q = b1v[obase + o_loc];
    f32x4 w2q = w2v[obase + o_loc];
#pragma unroll
    for (int nf = 0; nf < 4; ++nf) {
      int bat = wn * 64 + nf * 16 + frow;
      f32x4 q = acc[mf][nf];
      float v = 0.f;
#pragma unroll
      for (int j = 0; j < 4; ++j) {
        float hj = q[j] + b1q[j];
        hj = (hj >= 0.f) ? hj : 0.1f * hj;        // LeakyReLU(0.1)
        v += hj * w2q[j];
      }
      LE[bat * 68 + o_loc] = v;                   // banks 4(frow+mf)+jq -> free
    }
  }
  __builtin_amdgcn_s_barrier();

  const int col = t & 63, rowb = t >> 6;
  const float b2s = b2[obase + col];
  float* outB = out + (size_t)tileN * OUT_DIM + obase;
#pragma unroll
  for (int i = 0; i < 32; ++i) {
    int row = rowb + i * 4;
    outB[(size_t)row * OUT_DIM + col] = LE[row * 68 + col] + b2s;
  }
}

// ---- safety fallback (pure f32, used only if d_ws is too small) ----
__global__ __launch_bounds__(256) void fallback_kernel(
    const float* __restrict__ x, const float* __restrict__ W1,
    const float* __restrict__ b1, const float* __restrict__ W2,
    const float* __restrict__ b2, float* __restrict__ out) {
  int idx = blockIdx.x * 256 + threadIdx.x;
  if (idx >= BATCH * OUT_DIM) return;
  int bb = idx >> 10, o = idx & 1023;
  const float4* w1p = (const float4*)(W1 + (size_t)o * 4096);
  const float*  xp  = x + (size_t)bb * 1024;
  float4 acc = *(const float4*)(b1 + o * 4);
  for (int i = 0; i < 1024; ++i) {
    float xv = xp[i];
    float4 w = w1p[i];
    acc.x += xv * w.x; acc.y += xv * w.y; acc.z += xv * w.z; acc.w += xv * w.w;
  }
  float4 w2 = *(const float4*)(W2 + o * 4);
  float r = b2[o];
  r += ((acc.x >= 0.f) ? acc.x : 0.1f * acc.x) * w2.x;
  r += ((acc.y >= 0.f) ? acc.y : 0.1f * acc.y) * w2.y;
  r += ((acc.z >= 0.f) ? acc.z : 0.1f * acc.z) * w2.z;
  r += ((acc.w >= 0.f) ? acc.w : 0.1f * acc.w) * w2.w;
  out[(size_t)bb * OUT_DIM + o] = r;
}

extern "C" void kernel_launch(void* const* d_in, const int* in_sizes, int n_in,
                              void* d_out, int out_size, void* d_ws, size_t ws_size,
                              hipStream_t stream) {
  const float* x  = (const float*)d_in[0];
  const float* W1 = (const float*)d_in[1];
  const float* b1 = (const float*)d_in[2];
  const float* W2 = (const float*)d_in[3];
  const float* b2 = (const float*)d_in[4];
  float* out = (float*)d_out;

  size_t need = (size_t)BATCH * IN_DIM * 2 + (size_t)NCOL * IN_DIM * 2;  // 25.2 MB
  if (ws_size >= need) {
    unsigned short* xbf = (unsigned short*)d_ws;
    unsigned short* w1t = xbf + (size_t)BATCH * IN_DIM;
    cvt_x_kernel<<<(BATCH * IN_DIM / 4) / 256, 256, 0, stream>>>((const float4*)x, (ushort4*)xbf);
    cvt_w1t_kernel<<<(NCOL * IN_DIM / 4) / 256, 256, 0, stream>>>(W1, (ushort4*)w1t);
    mlp_gemm_kernel<<<(NCOL / 256) * (BATCH / 128), 256, 0, stream>>>(
        w1t, xbf, (const f32x4*)b1, (const f32x4*)W2, b2, out);
  } else {
    fallback_kernel<<<(BATCH * OUT_DIM + 255) / 256, 256, 0, stream>>>(x, W1, b1, W2, b2, out);
  }
}